// Round 2
// baseline (377.179 us; speedup 1.0000x reference)
//
#include <hip/hip_runtime.h>
#include <math.h>

#define DFEAT 128

// Pass 1: scatter segment boundaries. offs[a] = first row index with seg >= a.
// seg is sorted; every offs[0..A] entry gets written exactly once.
__global__ __launch_bounds__(256) void seg_bounds_kernel(
    const int* __restrict__ seg, int* __restrict__ offs, int total, int A)
{
    const int i = blockIdx.x * 256 + threadIdx.x;
    if (i >= total) return;
    const int s = seg[i];
    const int p = (i == 0) ? -1 : seg[i - 1];
    for (int a = p + 1; a <= s; ++a) offs[a] = i;      // usually 0 or 1 iter
    if (i == total - 1)
        for (int a = s + 1; a <= A; ++a) offs[a] = total;
}

// Pass 2: one block per anchor. Each half-wave (32 lanes x float4) owns one
// row per iteration -> a 64-lane wave reads 2 contiguous rows = 1 KiB
// coalesced. Anchor vector lives in registers (one float4 per lane),
// loaded once per block. Block-local log1p, single atomicAdd to d_out.
__global__ __launch_bounds__(256) void icc_anchor_kernel(
    const float* __restrict__ anchors,
    const float* __restrict__ Xn,
    const int*   __restrict__ offs,
    float*       __restrict__ out,
    float inv_total)
{
    const int a    = blockIdx.x;
    const int tid  = threadIdx.x;
    const int lane = tid & 31;   // lane within half-wave
    const int hw   = tid >> 5;   // half-wave id (0..7)
    const float eps = 1e-4f / (float)DFEAT;

    const int lo = offs[a];
    const int hi = offs[a + 1];

    // Anchor fragment for this lane's 4 columns — loaded once.
    const float4 av = *reinterpret_cast<const float4*>(
        anchors + (size_t)a * DFEAT + lane * 4);

    float dsum = 0.0f;
    for (int row = lo + hw; row < hi; row += 8) {
        const float4 x = *reinterpret_cast<const float4*>(
            Xn + (size_t)row * DFEAT + lane * 4);
        const float dx = x.x - av.x;
        const float dy = x.y - av.y;
        const float dz = x.z - av.z;
        const float dw = x.w - av.w;
        float sq = dx * dx + dy * dy + dz * dz + dw * dw;
        #pragma unroll
        for (int off = 16; off > 0; off >>= 1)
            sq += __shfl_down(sq, off, 32);
        if (lane == 0) dsum += sqrtf(sq + eps);
    }

    __shared__ float part[8];
    if (lane == 0) part[hw] = dsum;
    __syncthreads();
    if (tid == 0) {
        float s = 0.0f;
        #pragma unroll
        for (int h = 0; h < 8; ++h) s += part[h];
        atomicAdd(out, log1pf(s) * inv_total);
    }
}

extern "C" void kernel_launch(void* const* d_in, const int* in_sizes, int n_in,
                              void* d_out, int out_size, void* d_ws, size_t ws_size,
                              hipStream_t stream) {
    const float* anchors = (const float*)d_in[0];
    const float* Xn      = (const float*)d_in[1];
    const int*   seg     = (const int*)d_in[2];
    float* out = (float*)d_out;

    const int A     = in_sizes[0] / DFEAT;   // 1024
    const int total = in_sizes[2];           // 524288

    int* offs = (int*)d_ws;                  // A+1 ints

    hipMemsetAsync(out, 0, sizeof(float), stream);
    seg_bounds_kernel<<<(total + 255) / 256, 256, 0, stream>>>(seg, offs, total, A);
    icc_anchor_kernel<<<A, 256, 0, stream>>>(anchors, Xn, offs, out,
                                             1.0f / (float)total);
}

// Round 3
// 374.479 us; speedup vs baseline: 1.0072x; 1.0072x over previous
//
#include <hip/hip_runtime.h>
#include <math.h>

#define DFEAT 128
#define BLOCK 512   // 8 waves; 1024 blocks / 256 CU = 4 blocks/CU = 32 waves/CU

// One block per anchor. Quad-per-row: lanes (l4=0..3) each load a float4, so a
// quad covers 64B; k=0..7 walks the 512B row. Per load instruction the wave
// reads 16 rows x 64B = 1 KiB of fully-consumed cache lines. Row reduction is
// 2 wave-wide shfl_xor(width=4) per 16 rows instead of 5 serial shfls per row.
__global__ __launch_bounds__(BLOCK) void icc_anchor_kernel(
    const float* __restrict__ anchors,
    const float* __restrict__ Xn,
    const int*   __restrict__ seg,
    float*       __restrict__ out,
    int total, float inv_total)
{
    const int a   = blockIdx.x;
    const int tid = threadIdx.x;
    __shared__ int   bnd[2];
    __shared__ float part[BLOCK / 64];

    // Two threads binary-search the sorted seg array for [lo, hi).
    if (tid >= BLOCK - 2) {
        const int key = a + (tid & 1);     // lower_bound(key)
        int lo = 0, hi = total;
        while (lo < hi) {
            const int m = (lo + hi) >> 1;
            if (seg[m] < key) lo = m + 1; else hi = m;
        }
        bnd[tid & 1] = lo;
    }

    const int l4 = tid & 3;          // lane in quad
    const int q  = (tid & 63) >> 2;  // quad in wave (0..15)
    const int w  = tid >> 6;         // wave (0..7)
    const float eps = 1e-4f / (float)DFEAT;

    // Anchor fragment: depends only on (l4, k) -> one 64B line per k for the
    // whole wave, L1-broadcast. 32 VGPRs, loaded once.
    float4 afrag[8];
    #pragma unroll
    for (int k = 0; k < 8; ++k)
        afrag[k] = *reinterpret_cast<const float4*>(
            anchors + (size_t)a * DFEAT + k * 16 + l4 * 4);

    __syncthreads();
    const int lo = bnd[0], hi = bnd[1];

    float dsum = 0.0f;   // stays 0 on l4 != 0 lanes
    for (int row = lo + w * 16 + q; row < hi; row += BLOCK / 4) {
        const float* rp = Xn + (size_t)row * DFEAT + l4 * 4;
        float sq = 0.0f;
        #pragma unroll
        for (int k = 0; k < 8; ++k) {
            const float4 x = *reinterpret_cast<const float4*>(rp + k * 16);
            const float dx = x.x - afrag[k].x;
            const float dy = x.y - afrag[k].y;
            const float dz = x.z - afrag[k].z;
            const float dw = x.w - afrag[k].w;
            sq += dx * dx + dy * dy + dz * dz + dw * dw;
        }
        // quad reduction: all 4 lanes end with the row's full sum
        sq += __shfl_xor(sq, 1, 4);
        sq += __shfl_xor(sq, 2, 4);
        if (l4 == 0) dsum += sqrtf(sq + eps);
    }

    // wave reduction (non-leader lanes hold 0)
    #pragma unroll
    for (int off = 32; off > 0; off >>= 1)
        dsum += __shfl_down(dsum, off, 64);
    if ((tid & 63) == 0) part[w] = dsum;
    __syncthreads();
    if (tid == 0) {
        float s = 0.0f;
        #pragma unroll
        for (int h = 0; h < BLOCK / 64; ++h) s += part[h];
        atomicAdd(out, log1pf(s) * inv_total);
    }
}

extern "C" void kernel_launch(void* const* d_in, const int* in_sizes, int n_in,
                              void* d_out, int out_size, void* d_ws, size_t ws_size,
                              hipStream_t stream) {
    const float* anchors = (const float*)d_in[0];
    const float* Xn      = (const float*)d_in[1];
    const int*   seg     = (const int*)d_in[2];
    float* out = (float*)d_out;

    const int A     = in_sizes[0] / DFEAT;   // 1024
    const int total = in_sizes[2];           // 524288

    hipMemsetAsync(out, 0, sizeof(float), stream);
    icc_anchor_kernel<<<A, BLOCK, 0, stream>>>(anchors, Xn, seg, out,
                                               total, 1.0f / (float)total);
}